// Round 5
// baseline (363.829 us; speedup 1.0000x reference)
//
#include <hip/hip_runtime.h>
#include <hip/hip_bf16.h>
#include <stdint.h>
#include <stddef.h>

// Problem constants (fixed by the reference)
#define B_DIM 4
#define NH    16
#define LSEQ  2048
#define HD    64
#define DM    1024
#define TOKENS (B_DIM * LSEQ)   // 8192

typedef __bf16 bf16_t;
typedef __attribute__((ext_vector_type(8))) __bf16 bf16x8;
typedef __attribute__((ext_vector_type(4))) __bf16 bf16x4;
typedef __attribute__((ext_vector_type(4))) float  f32x4;

// async global->LDS, 16B per lane, lane i lands at ldsbase + i*16
#define GLD16(gp, lp) \
  __builtin_amdgcn_global_load_lds((__attribute__((address_space(1))) void*)(gp), \
                                   (__attribute__((address_space(3))) void*)(lp), 16, 0, 0)

// raw sync primitives (T4: counted vmcnt, NEVER vmcnt(0) drain in main loop)
#define WAITV8 asm volatile("s_waitcnt vmcnt(8)" ::: "memory")
#define WAITV4 asm volatile("s_waitcnt vmcnt(4)" ::: "memory")
#define WAITV0 asm volatile("s_waitcnt vmcnt(0)" ::: "memory")
#define WAITL0 asm volatile("s_waitcnt lgkmcnt(0)" ::: "memory")
#define SBAR   __builtin_amdgcn_s_barrier()
#define SCHED0 __builtin_amdgcn_sched_barrier(0)

__device__ __forceinline__ f32x4 mfma_16x16x32(bf16x8 a, bf16x8 b, f32x4 c) {
  return __builtin_amdgcn_mfma_f32_16x16x32_bf16(a, b, c, 0, 0, 0);
}

// ---------------------------------------------------------------------------
// Casts: 3 activations (dst contiguous: xq,xk,xv) / 4 weights (wq,wk,wv,wo)
// ---------------------------------------------------------------------------
__global__ __launch_bounds__(256) void cast3_kernel(const float* __restrict__ a,
                                                    const float* __restrict__ b,
                                                    const float* __restrict__ c,
                                                    bf16_t* __restrict__ dst, int n) {
  const float* src = (blockIdx.y == 0) ? a : (blockIdx.y == 1) ? b : c;
  const int i = (blockIdx.x * 256 + threadIdx.x) * 4;
  if (i < n) {
    const float4 v = *(const float4*)(src + i);
    bf16x4 o;
    o[0] = (bf16_t)v.x; o[1] = (bf16_t)v.y; o[2] = (bf16_t)v.z; o[3] = (bf16_t)v.w;
    *(bf16x4*)(dst + (size_t)blockIdx.y * n + i) = o;
  }
}

__global__ __launch_bounds__(256) void cast4_kernel(const float* __restrict__ a,
                                                    const float* __restrict__ b,
                                                    const float* __restrict__ c,
                                                    const float* __restrict__ d,
                                                    bf16_t* __restrict__ dst, int n) {
  const float* src = (blockIdx.y == 0) ? a : (blockIdx.y == 1) ? b
                   : (blockIdx.y == 2) ? c : d;
  const int i = (blockIdx.x * 256 + threadIdx.x) * 4;
  if (i < n) {
    const float4 v = *(const float4*)(src + i);
    bf16x4 o;
    o[0] = (bf16_t)v.x; o[1] = (bf16_t)v.y; o[2] = (bf16_t)v.z; o[3] = (bf16_t)v.w;
    *(bf16x4*)(dst + (size_t)blockIdx.y * n + i) = o;
  }
}

// GEMM tile body: 3-deep counted-vmcnt pipeline (round-5).
// Round-4's 2-deep gave the prefetch only ~1 K-step (~400cy) of cover —
// less than L2/L3 hit latency, so every vmcnt(4) stalled. 3 buffers give
// ~2 K-steps (~800cy). Tile t's 4 loads are the oldest of <=12 in flight
// -> vmcnt(8) suffices (4/0 only in the 2-tile tail). Prefetch of t+3 goes
// into buf[t%3] (just freed), issued AFTER the read-done barrier.
#define GEMM_TILE(CUR, WAIT, PRE, KK2)                                        \
  {                                                                           \
    WAIT; SBAR; SCHED0;                                                       \
    const bf16_t* Ac = &As[CUR][0];                                           \
    const bf16_t* Bc = &Bs[CUR][0];                                           \
    bf16x8 af[4], bfr[4];                                                     \
    _Pragma("unroll") for (int i_ = 0; i_ < 4; ++i_)                          \
      af[i_] = *(const bf16x8*)(Ac + (wm + i_ * 16 + l16) * 32 + fcol);       \
    _Pragma("unroll") for (int j_ = 0; j_ < 4; ++j_)                          \
      bfr[j_] = *(const bf16x8*)(Bc + (wn + j_ * 16 + l16) * 32 + fcol);      \
    _Pragma("unroll") for (int i_ = 0; i_ < 4; ++i_)                          \
      _Pragma("unroll") for (int j_ = 0; j_ < 4; ++j_)                        \
        acc[i_][j_] = mfma_16x16x32(af[i_], bfr[j_], acc[i_][j_]);            \
    WAITL0; SBAR; SCHED0;                                                     \
    if (PRE) {                                                                \
      const int kk2_ = (KK2);                                                 \
      GLD16(Ag0 + kk2_, &As[CUR][0] + ld0);                                   \
      GLD16(Ag1 + kk2_, &As[CUR][0] + ld1);                                   \
      GLD16(Bg0 + kk2_, &Bs[CUR][0] + ld0);                                   \
      GLD16(Bg1 + kk2_, &Bs[CUR][0] + ld1);                                   \
    }                                                                         \
  }

// 32 tiles: prologue stages 0,1,2; main loop 27 tiles; 5-tile tail.
#define GEMM_LOOP                                                             \
  GLD16(Ag0, &As[0][0] + ld0); GLD16(Ag1, &As[0][0] + ld1);                   \
  GLD16(Bg0, &Bs[0][0] + ld0); GLD16(Bg1, &Bs[0][0] + ld1);                   \
  GLD16(Ag0 + 32, &As[1][0] + ld0); GLD16(Ag1 + 32, &As[1][0] + ld1);         \
  GLD16(Bg0 + 32, &Bs[1][0] + ld0); GLD16(Bg1 + 32, &Bs[1][0] + ld1);         \
  GLD16(Ag0 + 64, &As[2][0] + ld0); GLD16(Ag1 + 64, &As[2][0] + ld1);         \
  GLD16(Bg0 + 64, &Bs[2][0] + ld0); GLD16(Bg1 + 64, &Bs[2][0] + ld1);         \
  for (int ii = 0; ii < 9; ++ii) {                                            \
    const int kkb = ii * 96 + 96;                                             \
    GEMM_TILE(0, WAITV8, true, kkb);                                          \
    GEMM_TILE(1, WAITV8, true, kkb + 32);                                     \
    GEMM_TILE(2, WAITV8, true, kkb + 64);                                     \
  }                                                                           \
  GEMM_TILE(0, WAITV8, true, 960);                                            \
  GEMM_TILE(1, WAITV8, true, 992);                                            \
  GEMM_TILE(2, WAITV8, false, 0);                                             \
  GEMM_TILE(0, WAITV4, false, 0);                                             \
  GEMM_TILE(1, WAITV0, false, 0);

// ---------------------------------------------------------------------------
// Fused QKV projection: ONE dispatch, blockIdx.z in {0,1,2} = q,k,v.
// 128x128-tile bf16 GEMM; swizzled LDS (r3: conflicts 6.29M->0), 3-deep
// counted-vmcnt pipeline (r5), XCD-aware tile remap (T1): XCD a owns
// m-tiles [8a,8a+8) for all n -> A-panel (2MB) + B (2MB) resident per-XCD L2.
// ---------------------------------------------------------------------------
__global__ __launch_bounds__(256) void qkv_proj_kernel(const bf16_t* __restrict__ X,
                                                       const bf16_t* __restrict__ Wb,
                                                       const float* __restrict__ bq,
                                                       const float* __restrict__ bk,
                                                       const float* __restrict__ bv,
                                                       const float* __restrict__ cos_q,
                                                       const float* __restrict__ sin_q,
                                                       const float* __restrict__ cos_k,
                                                       const float* __restrict__ sin_k,
                                                       bf16_t* __restrict__ qtb,
                                                       bf16_t* __restrict__ ktb,
                                                       bf16_t* __restrict__ vtb) {
  __shared__ bf16_t As[3][128 * 32];
  __shared__ bf16_t Bs[3][128 * 32];
  const int z = blockIdx.z;
  const bf16_t* A  = X  + (size_t)z * TOKENS * DM;
  const bf16_t* Bw = Wb + (size_t)z * DM * DM;
  const float* bias = (z == 0) ? bq : (z == 1) ? bk : bv;

  const int tid  = threadIdx.x;
  const int wave = tid >> 6, lane = tid & 63;
  const int quad = lane >> 4, l16 = lane & 15;
  // XCD remap: linear id L -> XCD L%8 (round-robin); give XCD a the m-chunk
  // [8a,8a+8) across all n (bijective over 512 per z)
  const int L  = blockIdx.x + (blockIdx.y << 6);
  const int mt = ((L & 7) << 3) | ((L >> 3) & 7);
  const int nt = L >> 6;
  const int m0 = mt * 128, n0 = nt * 128;
  const int wm = (wave >> 1) * 64, wn = (wave & 1) * 64;

  f32x4 acc[4][4];
#pragma unroll
  for (int i = 0; i < 4; ++i)
#pragma unroll
    for (int j = 0; j < 4; ++j) acc[i][j] = (f32x4){0.f, 0.f, 0.f, 0.f};

  // staging: lane covers LDS (row = c*16 + lane>>2, blk = lane&3); source
  // col-block pre-swizzled so LDS (row,blk) holds global blk^((row>>1)&3)
  const int srow = lane >> 2;
  const int scol = ((lane & 3) ^ ((lane >> 3) & 3)) * 8;
  const int c0 = wave * 2, c1 = c0 + 1;
  const int r0 = c0 * 16 + srow, r1 = c1 * 16 + srow;
  const bf16_t* Ag0 = A  + (size_t)(m0 + r0) * DM + scol;
  const bf16_t* Ag1 = A  + (size_t)(m0 + r1) * DM + scol;
  const bf16_t* Bg0 = Bw + (size_t)(n0 + r0) * DM + scol;
  const bf16_t* Bg1 = Bw + (size_t)(n0 + r1) * DM + scol;
  const int ld0 = c0 * 512, ld1 = c1 * 512;

  // fragment reads: XOR by (l16>>1)&3 (row = wm/wn + i*16 + l16; wm,16i == 0 mod 8)
  const int fcol = ((quad ^ ((l16 >> 1) & 3)) << 3);

  GEMM_LOOP

  // epilogue: C row = quad*4+reg, col = l16 (m89-verified C/D layout)
  if (z < 2) {
    const float* cosb = (z == 0) ? cos_q : cos_k;
    const float* sinb = (z == 0) ? sin_q : sin_k;
    bf16_t* out = (z == 0) ? qtb : ktb;
    const int h = (n0 + wn) >> 6;
#pragma unroll
    for (int i = 0; i < 4; ++i) {
#pragma unroll
      for (int j = 0; j < 2; ++j) {
        const int hd1 = j * 16 + l16;
        const int hd2 = hd1 + 32;
        const float bn1 = bias[n0 + wn + hd1];
        const float bn2 = bias[n0 + wn + hd2];
#pragma unroll
        for (int r = 0; r < 4; ++r) {
          const int m = m0 + wm + i * 16 + quad * 4 + r;
          const int b = m >> 11, l = m & (LSEQ - 1);
          const size_t cb = ((size_t)b * LSEQ + l) * HD;
          const float x1 = (float)(bf16_t)(acc[i][j][r] + bn1);
          const float x2 = (float)(bf16_t)(acc[i][j + 2][r] + bn2);
          const float c1 = cosb[cb + hd1], s1 = sinb[cb + hd1];
          const float c2 = cosb[cb + hd2], s2 = sinb[cb + hd2];
          bf16_t* dst = out + (((size_t)(b * NH + h)) * LSEQ + l) * HD;
          dst[hd1] = (bf16_t)(x1 * c1 - x2 * s1);
          dst[hd2] = (bf16_t)(x2 * c2 + x1 * s2);
        }
      }
    }
  } else {
#pragma unroll
    for (int i = 0; i < 4; ++i) {
      const int mb = m0 + wm + i * 16 + quad * 4;
      const int b = mb >> 11, l = mb & (LSEQ - 1);
#pragma unroll
      for (int j = 0; j < 4; ++j) {
        const int n = n0 + wn + j * 16 + l16;
        const int h = n >> 6, hd = n & (HD - 1);
        const float bn = bias[n];
        bf16x4 pk;
#pragma unroll
        for (int r = 0; r < 4; ++r) pk[r] = (bf16_t)(acc[i][j][r] + bn);
        *(bf16x4*)(vtb + (((size_t)(b * NH + h)) * HD + hd) * LSEQ + l) = pk;
      }
    }
  }
}

// ---------------------------------------------------------------------------
// Out projection: C = A * Wo^T + bo, f32 store (r5: 3-deep + XCD remap)
// ---------------------------------------------------------------------------
__global__ __launch_bounds__(256) void out_gemm_kernel(const bf16_t* __restrict__ A,
                                                       const bf16_t* __restrict__ Bw,
                                                       const float* __restrict__ bias,
                                                       float* __restrict__ out) {
  __shared__ bf16_t As[3][128 * 32];
  __shared__ bf16_t Bs[3][128 * 32];
  const int tid  = threadIdx.x;
  const int wave = tid >> 6, lane = tid & 63;
  const int quad = lane >> 4, l16 = lane & 15;
  const int L  = blockIdx.x + (blockIdx.y << 6);
  const int mt = ((L & 7) << 3) | ((L >> 3) & 7);
  const int nt = L >> 6;
  const int m0 = mt * 128, n0 = nt * 128;
  const int wm = (wave >> 1) * 64, wn = (wave & 1) * 64;

  f32x4 acc[4][4];
#pragma unroll
  for (int i = 0; i < 4; ++i)
#pragma unroll
    for (int j = 0; j < 4; ++j) acc[i][j] = (f32x4){0.f, 0.f, 0.f, 0.f};

  const int srow = lane >> 2;
  const int scol = ((lane & 3) ^ ((lane >> 3) & 3)) * 8;
  const int c0 = wave * 2, c1 = c0 + 1;
  const int r0 = c0 * 16 + srow, r1 = c1 * 16 + srow;
  const bf16_t* Ag0 = A  + (size_t)(m0 + r0) * DM + scol;
  const bf16_t* Ag1 = A  + (size_t)(m0 + r1) * DM + scol;
  const bf16_t* Bg0 = Bw + (size_t)(n0 + r0) * DM + scol;
  const bf16_t* Bg1 = Bw + (size_t)(n0 + r1) * DM + scol;
  const int ld0 = c0 * 512, ld1 = c1 * 512;
  const int fcol = ((quad ^ ((l16 >> 1) & 3)) << 3);

  GEMM_LOOP

#pragma unroll
  for (int i = 0; i < 4; ++i)
#pragma unroll
    for (int j = 0; j < 4; ++j) {
      const int n  = n0 + wn + j * 16 + l16;
      const float bn = bias[n];
#pragma unroll
      for (int r = 0; r < 4; ++r) {
        const int m = m0 + wm + i * 16 + quad * 4 + r;
        out[(size_t)m * DM + n] = acc[i][j][r] + bn;
      }
    }
}

// ---------------------------------------------------------------------------
// Flash attention v7: r5 changes on top of v6:
//  - T4 counted-vmcnt sync (WAITV4/SBAR) replaces __syncthreads 2-buf: the
//    old barrier's implicit vmcnt(0) drained the prefetch every tile
//    (~200-400cy x 32). Now tile t+2's loads ride across both barriers.
//  - XCD remap: XCD a owns bh in [8a,8a+8) = 128 blocks = one XCD's full
//    residency; K/V working set 4MB = its L2. Cuts the 139MB (~3x
//    compulsory) L2-miss traffic and its latency.
//  - mflag sync via lgkmcnt(0)+s_barrier (non-draining).
// Keeps: sigma-permuted K staging, in-register P transpose, XOR swizzle,
// mask pre-scan, l via ones-MFMA.
// ---------------------------------------------------------------------------
#define ATTN_TILE(K0)                                                         \
  {                                                                           \
    const bf16_t* Kc = &Kl[cur][0];                                           \
    const bf16_t* Vc = &Vl[cur][0];                                           \
    f32x4 S[2][4];                                                            \
    _Pragma("unroll") for (int j = 0; j < 4; ++j) {                           \
      const bf16x8 kb0 = *(const bf16x8*)(Kc + oA + j * 1024);                \
      const bf16x8 kb1 = *(const bf16x8*)(Kc + oB + j * 1024);                \
      _Pragma("unroll") for (int u = 0; u < 2; ++u) {                         \
        f32x4 a = (f32x4){0.f, 0.f, 0.f, 0.f};                                \
        a = mfma_16x16x32(kb0, qa[u][0], a);                                  \
        a = mfma_16x16x32(kb1, qa[u][1], a);                                  \
        _Pragma("unroll") for (int r = 0; r < 4; ++r)                         \
          S[u][j][r] = __builtin_amdgcn_exp2f(a[r] * scale_l2e);              \
      }                                                                       \
    }                                                                         \
    if (has_mask) {                                                           \
      const uint64_t mlo = *(const uint64_t*)(mrow + (K0) + quad * 8);        \
      const uint64_t mhi = *(const uint64_t*)(mrow + (K0) + 32 + quad * 8);   \
      if (!__all((mlo | mhi) == 0)) {                                         \
        _Pragma("unroll") for (int j = 0; j < 4; ++j) {                       \
          const uint64_t mm = (j & 2) ? mhi : mlo;                            \
          _Pragma("unroll") for (int r = 0; r < 4; ++r)                       \
            if ((mm >> (((j & 1) * 4 + r) * 8)) & 0xff) {                     \
              S[0][j][r] = 0.f;                                               \
              S[1][j][r] = 0.f;                                               \
            }                                                                 \
        }                                                                     \
      }                                                                       \
    }                                                                         \
    bf16x8 pa[2][2];                                                          \
    _Pragma("unroll") for (int u = 0; u < 2; ++u)                             \
      _Pragma("unroll") for (int f = 0; f < 2; ++f)                           \
        _Pragma("unroll") for (int e = 0; e < 8; ++e)                         \
          pa[u][f][e] = (bf16_t)S[u][2 * f + (e >> 2)][e & 3];                \
    _Pragma("unroll") for (int u = 0; u < 2; ++u) {                           \
      Ol[u] = mfma_16x16x32(pa[u][0], ones, Ol[u]);                           \
      Ol[u] = mfma_16x16x32(pa[u][1], ones, Ol[u]);                           \
    }                                                                         \
    _Pragma("unroll") for (int jd = 0; jd < 4; ++jd) {                        \
      const bf16x8 vb0 = *(const bf16x8*)(Vc + oA + jd * 1024);               \
      const bf16x8 vb1 = *(const bf16x8*)(Vc + oB + jd * 1024);               \
      _Pragma("unroll") for (int u = 0; u < 2; ++u) {                         \
        O[u][jd] = mfma_16x16x32(pa[u][0], vb0, O[u][jd]);                    \
        O[u][jd] = mfma_16x16x32(pa[u][1], vb1, O[u][jd]);                    \
      }                                                                       \
    }                                                                         \
  }

__global__ __launch_bounds__(256, 4) void attn_kernel(const bf16_t* __restrict__ qt,
                                                      const bf16_t* __restrict__ kt,
                                                      const bf16_t* __restrict__ vt,
                                                      const unsigned char* __restrict__ mask,
                                                      bf16_t* __restrict__ ctx) {
  __shared__ bf16_t Kl[2][64 * 64];        // [pos][d], col-blocks swizzled by pos&7
  __shared__ bf16_t Vl[2][64 * 64];        // [d][kk],  col-blocks swizzled by d&7
  __shared__ int mflag;
  // XCD remap: XCD a <- bh in [8a,8a+8), all 16 q-tiles (bijective over 1024)
  const int L  = blockIdx.x + (blockIdx.y << 4);
  const int bh = ((L & 7) << 3) | ((L >> 3) & 7);
  const int q0 = (L >> 6) * 128;
  const int b = bh >> 4, h = bh & (NH - 1);
  const int tid = threadIdx.x;
  const int wave = tid >> 6, lane = tid & 63;
  const int quad = lane >> 4, l16 = lane & 15;
  const float scale_l2e = 0.125f * 1.44269504f;  // HD^-0.5 * log2(e)

  const bf16_t* kbase = kt + (size_t)bh * LSEQ * HD;
  const bf16_t* vbase = vt + (size_t)bh * HD * LSEQ;
  const unsigned char* mrow = mask + (size_t)b * LSEQ;

  if (tid == 0) mflag = 0;
  __syncthreads();
  // mask pre-scan: 256 threads x 8B = entire 2048B row
  {
    const uint64_t mw = ((const uint64_t*)mrow)[tid];
    if (mw != 0) atomicOr(&mflag, 1);
  }

  // Q fragments (m=l16, k=quad*8+e), used as B-operand of swapped QK^T
  bf16x8 qa[2][2];
#pragma unroll
  for (int u = 0; u < 2; ++u) {
    const bf16_t* qrow = qt + (((size_t)bh * LSEQ) + q0 + wave * 32 + u * 16 + l16) * HD;
    qa[u][0] = *(const bf16x8*)(qrow + quad * 8);
    qa[u][1] = *(const bf16x8*)(qrow + 32 + quad * 8);
  }

  f32x4 O[2][4];
  f32x4 Ol[2];
#pragma unroll
  for (int u = 0; u < 2; ++u) {
    Ol[u] = (f32x4){0.f, 0.f, 0.f, 0.f};
#pragma unroll
    for (int j = 0; j < 4; ++j) O[u][j] = (f32x4){0.f, 0.f, 0.f, 0.f};
  }
  bf16x8 ones;
#pragma unroll
  for (int e = 0; e < 8; ++e) ones[e] = (bf16_t)1.0f;

  // --- hoisted per-lane offsets ---
  const int srow8 = lane >> 3;  // 0..7 within 8-row chunk
  const int scb   = lane & 7;   // LDS col-block position
  const int c0 = wave * 2, c1 = c0 + 1;
  const int p0 = c0 * 8 + srow8, p1 = p0 + 8;
  const int g0 = (scb ^ srow8) * 8;   // p&7 == srow8 for both chunks
  const int sig0 = ((p0 >> 5) << 5) | (((p0 >> 2) & 3) << 3) | (((p0 >> 4) & 1) << 2) | (p0 & 3);
  const int sig1 = ((p1 >> 5) << 5) | (((p1 >> 2) & 3) << 3) | (((p1 >> 4) & 1) << 2) | (p1 & 3);
  const int kgo0 = sig0 * HD + g0, kgo1 = sig1 * HD + g0;      // K global lane offsets
  const int vgo0 = p0 * LSEQ + g0, vgo1 = p1 * LSEQ + g0;      // V global lane offsets
  const int ld0 = c0 * 512, ld1 = c1 * 512;                    // LDS dst offsets

  // fragment-read offsets: sw = (j*16+l16)&7 == l16&7 for all j
  const int sw  = l16 & 7;
  const int oA  = l16 * 64 + ((quad ^ sw) << 3);
  const int oB  = l16 * 64 + (((quad + 4) ^ sw) << 3);

  // prologue: stage tiles 0 and 1 (K rows sigma-permuted); 8 loads in flight
  GLD16(kbase + kgo0, &Kl[0][0] + ld0);
  GLD16(kbase + kgo1, &Kl[0][0] + ld1);
  GLD16(vbase + vgo0, &Vl[0][0] + ld0);
  GLD16(vbase + vgo1, &Vl[0][0] + ld1);
  GLD16(kbase + (size_t)64 * HD + kgo0, &Kl[1][0] + ld0);
  GLD16(kbase + (size_t)64 * HD + kgo1, &Kl[1][0] + ld1);
  GLD16(vbase + (size_t)(vgo0 + 64), &Vl[1][0] + ld0);
  GLD16(vbase + (size_t)(vgo1 + 64), &Vl[1][0] + ld1);

  // non-draining mflag sync: own atomic done (lgkm), then barrier, then read
  WAITL0; SBAR;
  const bool has_mask = (mflag != 0);

  int cur = 0;
  for (int t = 0; t < 30; ++t) {
    WAITV4; SBAR; SCHED0;
    ATTN_TILE(t * 64);
    WAITL0; SBAR; SCHED0;
    {
      const int k0n = t * 64 + 128;
      bf16_t* Kd = &Kl[cur][0];
      bf16_t* Vd = &Vl[cur][0];
      GLD16(kbase + (size_t)k0n * HD + kgo0, Kd + ld0);
      GLD16(kbase + (size_t)k0n * HD + kgo1, Kd + ld1);
      GLD16(vbase + (size_t)(vgo0 + k0n), Vd + ld0);
      GLD16(vbase + (size_t)(vgo1 + k0n), Vd + ld1);
    }
    cur ^= 1;
  }
  // t=30: own loads are oldest 4 of 8
  WAITV4; SBAR; SCHED0;
  ATTN_TILE(30 * 64);
  cur ^= 1;
  // t=31: last tile
  WAITV0; SBAR; SCHED0;
  ATTN_TILE(31 * 64);

  // epilogue: normalize and write ctx [B, LSEQ, NH*HD] bf16 (token-major)
#pragma unroll
  for (int u = 0; u < 2; ++u) {
    f32x4 linv;
#pragma unroll
    for (int r = 0; r < 4; ++r) linv[r] = 1.0f / Ol[u][r];
#pragma unroll
    for (int jd = 0; jd < 4; ++jd)
#pragma unroll
      for (int r = 0; r < 4; ++r) {
        const int l = q0 + wave * 32 + u * 16 + quad * 4 + r;
        const int d = h * HD + jd * 16 + l16;
        const float o = O[u][jd][r] * linv[r];
        ctx[((size_t)b * LSEQ + l) * DM + d] = (bf16_t)o;
      }
  }
}

// ---------------------------------------------------------------------------
extern "C" void kernel_launch(void* const* d_in, const int* in_sizes, int n_in,
                              void* d_out, int out_size, void* d_ws, size_t ws_size,
                              hipStream_t stream) {
  (void)in_sizes; (void)n_in; (void)out_size; (void)ws_size;
  const float* query = (const float*)d_in[0];
  const float* key   = (const float*)d_in[1];
  const float* value = (const float*)d_in[2];
  const float* cos_q = (const float*)d_in[3];
  const float* sin_q = (const float*)d_in[4];
  const float* cos_k = (const float*)d_in[5];
  const float* sin_k = (const float*)d_in[6];
  const unsigned char* mask = (const unsigned char*)d_in[7];
  const float* Wq = (const float*)d_in[8];
  const float* bq = (const float*)d_in[9];
  const float* Wk = (const float*)d_in[10];
  const float* bk = (const float*)d_in[11];
  const float* Wv = (const float*)d_in[12];
  const float* bv = (const float*)d_in[13];
  const float* Wo = (const float*)d_in[14];
  const float* bo = (const float*)d_in[15];
  float* out = (float*)d_out;

  const size_t ACT = (size_t)TOKENS * DM;  // 8388608
  const size_t WEL = (size_t)DM * DM;      // 1048576

  bf16_t* p   = (bf16_t*)d_ws;
  bf16_t* xq  = p; p += ACT;    // xq,xk,xv contiguous (cast3 dst / qkv A base)
  bf16_t* xk  = p; p += ACT;
  bf16_t* xv  = p; p += ACT;
  bf16_t* wqb = p; p += WEL;    // wqb..wob contiguous (cast4 dst / qkv W base)
  bf16_t* wkb = p; p += WEL;
  bf16_t* wvb = p; p += WEL;
  bf16_t* wob = p; p += WEL;
  bf16_t* qtb = p; p += ACT;
  bf16_t* ktb = p; p += ACT;
  bf16_t* vtb = p; p += ACT;
  bf16_t* ctx = xk;  // alias: xk dead after qkv proj
  (void)xv; (void)wkb; (void)wvb;

  // casts (f32 -> bf16): 2 dispatches
  cast3_kernel<<<dim3((int)(ACT / 1024), 3), 256, 0, stream>>>(query, key, value, xq, (int)ACT);
  cast4_kernel<<<dim3((int)(WEL / 1024), 4), 256, 0, stream>>>(Wq, Wk, Wv, Wo, wqb, (int)WEL);

  // fused q/k/v projections (one dispatch, z = which projection)
  qkv_proj_kernel<<<dim3(TOKENS / 128, DM / 128, 3), 256, 0, stream>>>(
      xq, wqb, bq, bk, bv, cos_q, sin_q, cos_k, sin_k, qtb, ktb, vtb);

  // flash attention -> ctx [B, LSEQ, DM] bf16
  attn_kernel<<<dim3(LSEQ / 128, B_DIM * NH), 256, 0, stream>>>(qtb, ktb, vtb, mask, ctx);

  // output projection -> f32 d_out
  out_gemm_kernel<<<dim3(TOKENS / 128, DM / 128), 256, 0, stream>>>(ctx, wob, bo, out);
}

// Round 6
// 355.139 us; speedup vs baseline: 1.0245x; 1.0245x over previous
//
#include <hip/hip_runtime.h>
#include <hip/hip_bf16.h>
#include <stdint.h>
#include <stddef.h>

// Problem constants (fixed by the reference)
#define B_DIM 4
#define NH    16
#define LSEQ  2048
#define HD    64
#define DM    1024
#define TOKENS (B_DIM * LSEQ)   // 8192

typedef __bf16 bf16_t;
typedef __attribute__((ext_vector_type(8))) __bf16 bf16x8;
typedef __attribute__((ext_vector_type(4))) __bf16 bf16x4;
typedef __attribute__((ext_vector_type(4))) float  f32x4;

// async global->LDS, 16B per lane, lane i lands at ldsbase + i*16
#define GLD16(gp, lp) \
  __builtin_amdgcn_global_load_lds((__attribute__((address_space(1))) void*)(gp), \
                                   (__attribute__((address_space(3))) void*)(lp), 16, 0, 0)

// raw sync primitives (T4: counted vmcnt, NEVER vmcnt(0) drain in main loop)
#define WAITV4 asm volatile("s_waitcnt vmcnt(4)" ::: "memory")
#define WAITV0 asm volatile("s_waitcnt vmcnt(0)" ::: "memory")
#define WAITL0 asm volatile("s_waitcnt lgkmcnt(0)" ::: "memory")
#define SBAR   __builtin_amdgcn_s_barrier()
#define SCHED0 __builtin_amdgcn_sched_barrier(0)

__device__ __forceinline__ f32x4 mfma_16x16x32(bf16x8 a, bf16x8 b, f32x4 c) {
  return __builtin_amdgcn_mfma_f32_16x16x32_bf16(a, b, c, 0, 0, 0);
}

// ---------------------------------------------------------------------------
// Fused prep kernel (ONE dispatch): 1D grid decode.
//  [0, 24576)       : 3 activation casts f32->bf16 (q,k,v -> xq,xk,xv)
//  [24576, 28672)   : 4 weight casts f32->bf16 (Wq,Wk,Wv,Wo)
//  [28672, 29696)   : 2 interleaved (cos,sin) float2 tables (q,k) -> csq/csk.
//                     Tables live in d_out scratch (only out_gemm writes d_out,
//                     at the very end). Same f32 values -> qkv RoPE epilogue
//                     numerics bit-identical, but 2 loads/iter instead of 4.
// ---------------------------------------------------------------------------
__global__ __launch_bounds__(256) void prep_kernel(const float* __restrict__ q,
                                                   const float* __restrict__ k,
                                                   const float* __restrict__ v,
                                                   const float* __restrict__ Wq,
                                                   const float* __restrict__ Wk,
                                                   const float* __restrict__ Wv,
                                                   const float* __restrict__ Wo,
                                                   const float* __restrict__ cos_q,
                                                   const float* __restrict__ sin_q,
                                                   const float* __restrict__ cos_k,
                                                   const float* __restrict__ sin_k,
                                                   bf16_t* __restrict__ xdst,
                                                   bf16_t* __restrict__ wdst,
                                                   float2* __restrict__ cs) {
  const int bid = blockIdx.x;
  const int tid = threadIdx.x;
  if (bid < 24576) {                      // activation casts, n = TOKENS*DM
    const int s = bid >> 13, off = bid & 8191;
    const float* src = (s == 0) ? q : (s == 1) ? k : v;
    const int i = (off * 256 + tid) * 4;
    const float4 val = *(const float4*)(src + i);
    bf16x4 o;
    o[0] = (bf16_t)val.x; o[1] = (bf16_t)val.y; o[2] = (bf16_t)val.z; o[3] = (bf16_t)val.w;
    *(bf16x4*)(xdst + (size_t)s * (TOKENS * (size_t)DM) + i) = o;
  } else if (bid < 28672) {               // weight casts, n = DM*DM
    const int s = (bid - 24576) >> 10, off = (bid - 24576) & 1023;
    const float* src = (s == 0) ? Wq : (s == 1) ? Wk : (s == 2) ? Wv : Wo;
    const int i = (off * 256 + tid) * 4;
    const float4 val = *(const float4*)(src + i);
    bf16x4 o;
    o[0] = (bf16_t)val.x; o[1] = (bf16_t)val.y; o[2] = (bf16_t)val.z; o[3] = (bf16_t)val.w;
    *(bf16x4*)(wdst + (size_t)s * (DM * (size_t)DM) + i) = o;
  } else {                                // cs tables, n = TOKENS*HD = 524288
    const int s = (bid - 28672) >> 9, off = (bid - 28672) & 511;
    const float* cp = (s == 0) ? cos_q : cos_k;
    const float* sp = (s == 0) ? sin_q : sin_k;
    const int i = (off * 256 + tid) * 4;
    const float4 c4 = *(const float4*)(cp + i);
    const float4 s4 = *(const float4*)(sp + i);
    float2* d = cs + (size_t)s * (TOKENS * (size_t)HD) + i;
    d[0] = make_float2(c4.x, s4.x);
    d[1] = make_float2(c4.y, s4.y);
    d[2] = make_float2(c4.z, s4.z);
    d[3] = make_float2(c4.w, s4.w);
  }
}

// GEMM tile body (r4-proven config): 2-deep counted-vmcnt pipeline.
// This tile's 4 loads are the OLDEST outstanding -> vmcnt(4) suffices
// (vmcnt(0) only for the very last tile). Prefetch of tile i+2 is issued
// AFTER the read-done barrier and has a full iteration to land.
// (r5's 3-deep + XCD remap regressed 89.5->94: reverted.)
#define GEMM_TILE(CUR, WAIT, PRE, KK2)                                        \
  {                                                                           \
    WAIT; SBAR; SCHED0;                                                       \
    const bf16_t* Ac = &As[CUR][0];                                           \
    const bf16_t* Bc = &Bs[CUR][0];                                           \
    bf16x8 af[4], bfr[4];                                                     \
    _Pragma("unroll") for (int i_ = 0; i_ < 4; ++i_)                          \
      af[i_] = *(const bf16x8*)(Ac + (wm + i_ * 16 + l16) * 32 + fcol);       \
    _Pragma("unroll") for (int j_ = 0; j_ < 4; ++j_)                          \
      bfr[j_] = *(const bf16x8*)(Bc + (wn + j_ * 16 + l16) * 32 + fcol);      \
    _Pragma("unroll") for (int i_ = 0; i_ < 4; ++i_)                          \
      _Pragma("unroll") for (int j_ = 0; j_ < 4; ++j_)                        \
        acc[i_][j_] = mfma_16x16x32(af[i_], bfr[j_], acc[i_][j_]);            \
    WAITL0; SBAR; SCHED0;                                                     \
    if (PRE) {                                                                \
      const int kk2_ = (KK2);                                                 \
      GLD16(Ag0 + kk2_, &As[CUR][0] + ld0);                                   \
      GLD16(Ag1 + kk2_, &As[CUR][0] + ld1);                                   \
      GLD16(Bg0 + kk2_, &Bs[CUR][0] + ld0);                                   \
      GLD16(Bg1 + kk2_, &Bs[CUR][0] + ld1);                                   \
    }                                                                         \
  }

#define GEMM_LOOP                                                             \
  GLD16(Ag0, &As[0][0] + ld0); GLD16(Ag1, &As[0][0] + ld1);                   \
  GLD16(Bg0, &Bs[0][0] + ld0); GLD16(Bg1, &Bs[0][0] + ld1);                   \
  GLD16(Ag0 + 32, &As[1][0] + ld0); GLD16(Ag1 + 32, &As[1][0] + ld1);         \
  GLD16(Bg0 + 32, &Bs[1][0] + ld0); GLD16(Bg1 + 32, &Bs[1][0] + ld1);         \
  for (int ii = 0; ii < 15; ++ii) {                                           \
    const int kk2a = ii * 64 + 64;                                            \
    GEMM_TILE(0, WAITV4, true, kk2a);                                         \
    GEMM_TILE(1, WAITV4, true, kk2a + 32);                                    \
  }                                                                           \
  GEMM_TILE(0, WAITV4, false, 0);                                             \
  GEMM_TILE(1, WAITV0, false, 0);

// ---------------------------------------------------------------------------
// Fused QKV projection: ONE dispatch, blockIdx.z in {0,1,2} = q,k,v.
// 128x128-tile bf16 GEMM; swizzled LDS (r3: conflicts 6.29M->0), 2-deep
// counted-vmcnt pipeline (r4-proven, 89.5us). RoPE epilogue now reads the
// interleaved float2 (cos,sin) table: 64 loads/thread instead of 128,
// bit-identical values.
// ---------------------------------------------------------------------------
__global__ __launch_bounds__(256) void qkv_proj_kernel(const bf16_t* __restrict__ X,
                                                       const bf16_t* __restrict__ Wb,
                                                       const float* __restrict__ bq,
                                                       const float* __restrict__ bk,
                                                       const float* __restrict__ bv,
                                                       const float2* __restrict__ csq,
                                                       const float2* __restrict__ csk,
                                                       bf16_t* __restrict__ qtb,
                                                       bf16_t* __restrict__ ktb,
                                                       bf16_t* __restrict__ vtb) {
  __shared__ bf16_t As[2][128 * 32];
  __shared__ bf16_t Bs[2][128 * 32];
  const int z = blockIdx.z;
  const bf16_t* A  = X  + (size_t)z * TOKENS * DM;
  const bf16_t* Bw = Wb + (size_t)z * DM * DM;
  const float* bias = (z == 0) ? bq : (z == 1) ? bk : bv;

  const int tid  = threadIdx.x;
  const int wave = tid >> 6, lane = tid & 63;
  const int quad = lane >> 4, l16 = lane & 15;
  const int m0 = blockIdx.x * 128, n0 = blockIdx.y * 128;
  const int wm = (wave >> 1) * 64, wn = (wave & 1) * 64;

  f32x4 acc[4][4];
#pragma unroll
  for (int i = 0; i < 4; ++i)
#pragma unroll
    for (int j = 0; j < 4; ++j) acc[i][j] = (f32x4){0.f, 0.f, 0.f, 0.f};

  // staging: lane covers LDS (row = c*16 + lane>>2, blk = lane&3); source
  // col-block pre-swizzled so LDS (row,blk) holds global blk^((row>>1)&3)
  const int srow = lane >> 2;
  const int scol = ((lane & 3) ^ ((lane >> 3) & 3)) * 8;
  const int c0 = wave * 2, c1 = c0 + 1;
  const int r0 = c0 * 16 + srow, r1 = c1 * 16 + srow;
  const bf16_t* Ag0 = A  + (size_t)(m0 + r0) * DM + scol;
  const bf16_t* Ag1 = A  + (size_t)(m0 + r1) * DM + scol;
  const bf16_t* Bg0 = Bw + (size_t)(n0 + r0) * DM + scol;
  const bf16_t* Bg1 = Bw + (size_t)(n0 + r1) * DM + scol;
  const int ld0 = c0 * 512, ld1 = c1 * 512;

  // fragment reads: XOR by (l16>>1)&3 (row = wm/wn + i*16 + l16; wm,16i == 0 mod 8)
  const int fcol = ((quad ^ ((l16 >> 1) & 3)) << 3);

  GEMM_LOOP

  // epilogue: C row = quad*4+reg, col = l16 (m89-verified C/D layout)
  if (z < 2) {
    const float2* cst = (z == 0) ? csq : csk;
    bf16_t* out = (z == 0) ? qtb : ktb;
    const int h = (n0 + wn) >> 6;
#pragma unroll
    for (int i = 0; i < 4; ++i) {
#pragma unroll
      for (int j = 0; j < 2; ++j) {
        const int hd1 = j * 16 + l16;
        const int hd2 = hd1 + 32;
        const float bn1 = bias[n0 + wn + hd1];
        const float bn2 = bias[n0 + wn + hd2];
#pragma unroll
        for (int r = 0; r < 4; ++r) {
          const int m = m0 + wm + i * 16 + quad * 4 + r;
          const int b = m >> 11, l = m & (LSEQ - 1);
          const size_t cb = ((size_t)b * LSEQ + l) * HD;
          // explicit bf16 round BEFORE rope (verified numerics)
          const float x1 = (float)(bf16_t)(acc[i][j][r] + bn1);
          const float x2 = (float)(bf16_t)(acc[i][j + 2][r] + bn2);
          const float2 cs1 = cst[cb + hd1];
          const float2 cs2 = cst[cb + hd2];
          bf16_t* dst = out + (((size_t)(b * NH + h)) * LSEQ + l) * HD;
          dst[hd1] = (bf16_t)(x1 * cs1.x - x2 * cs1.y);
          dst[hd2] = (bf16_t)(x2 * cs2.x + x1 * cs2.y);
        }
      }
    }
  } else {
#pragma unroll
    for (int i = 0; i < 4; ++i) {
      const int mb = m0 + wm + i * 16 + quad * 4;
      const int b = mb >> 11, l = mb & (LSEQ - 1);
#pragma unroll
      for (int j = 0; j < 4; ++j) {
        const int n = n0 + wn + j * 16 + l16;
        const int h = n >> 6, hd = n & (HD - 1);
        const float bn = bias[n];
        bf16x4 pk;
#pragma unroll
        for (int r = 0; r < 4; ++r) pk[r] = (bf16_t)(acc[i][j][r] + bn);
        *(bf16x4*)(vtb + (((size_t)(b * NH + h)) * HD + hd) * LSEQ + l) = pk;
      }
    }
  }
}

// ---------------------------------------------------------------------------
// Out projection: C = A * Wo^T + bo, f32 store (r4-proven config)
// ---------------------------------------------------------------------------
__global__ __launch_bounds__(256) void out_gemm_kernel(const bf16_t* __restrict__ A,
                                                       const bf16_t* __restrict__ Bw,
                                                       const float* __restrict__ bias,
                                                       float* __restrict__ out) {
  __shared__ bf16_t As[2][128 * 32];
  __shared__ bf16_t Bs[2][128 * 32];
  const int tid  = threadIdx.x;
  const int wave = tid >> 6, lane = tid & 63;
  const int quad = lane >> 4, l16 = lane & 15;
  const int m0 = blockIdx.x * 128, n0 = blockIdx.y * 128;
  const int wm = (wave >> 1) * 64, wn = (wave & 1) * 64;

  f32x4 acc[4][4];
#pragma unroll
  for (int i = 0; i < 4; ++i)
#pragma unroll
    for (int j = 0; j < 4; ++j) acc[i][j] = (f32x4){0.f, 0.f, 0.f, 0.f};

  const int srow = lane >> 2;
  const int scol = ((lane & 3) ^ ((lane >> 3) & 3)) * 8;
  const int c0 = wave * 2, c1 = c0 + 1;
  const int r0 = c0 * 16 + srow, r1 = c1 * 16 + srow;
  const bf16_t* Ag0 = A  + (size_t)(m0 + r0) * DM + scol;
  const bf16_t* Ag1 = A  + (size_t)(m0 + r1) * DM + scol;
  const bf16_t* Bg0 = Bw + (size_t)(n0 + r0) * DM + scol;
  const bf16_t* Bg1 = Bw + (size_t)(n0 + r1) * DM + scol;
  const int ld0 = c0 * 512, ld1 = c1 * 512;
  const int fcol = ((quad ^ ((l16 >> 1) & 3)) << 3);

  GEMM_LOOP

#pragma unroll
  for (int i = 0; i < 4; ++i)
#pragma unroll
    for (int j = 0; j < 4; ++j) {
      const int n  = n0 + wn + j * 16 + l16;
      const float bn = bias[n];
#pragma unroll
      for (int r = 0; r < 4; ++r) {
        const int m = m0 + wm + i * 16 + quad * 4 + r;
        out[(size_t)m * DM + n] = acc[i][j][r] + bn;
      }
    }
}

// ---------------------------------------------------------------------------
// Flash attention v7 (unchanged from r5): T4 counted-vmcnt 2-deep, XCD remap,
// sigma-permuted K staging, in-register P transpose, XOR swizzle, mask
// pre-scan, l via ones-MFMA.
// ---------------------------------------------------------------------------
#define ATTN_TILE(K0)                                                         \
  {                                                                           \
    const bf16_t* Kc = &Kl[cur][0];                                           \
    const bf16_t* Vc = &Vl[cur][0];                                           \
    f32x4 S[2][4];                                                            \
    _Pragma("unroll") for (int j = 0; j < 4; ++j) {                           \
      const bf16x8 kb0 = *(const bf16x8*)(Kc + oA + j * 1024);                \
      const bf16x8 kb1 = *(const bf16x8*)(Kc + oB + j * 1024);                \
      _Pragma("unroll") for (int u = 0; u < 2; ++u) {                         \
        f32x4 a = (f32x4){0.f, 0.f, 0.f, 0.f};                                \
        a = mfma_16x16x32(kb0, qa[u][0], a);                                  \
        a = mfma_16x16x32(kb1, qa[u][1], a);                                  \
        _Pragma("unroll") for (int r = 0; r < 4; ++r)                         \
          S[u][j][r] = __builtin_amdgcn_exp2f(a[r] * scale_l2e);              \
      }                                                                       \
    }                                                                         \
    if (has_mask) {                                                           \
      const uint64_t mlo = *(const uint64_t*)(mrow + (K0) + quad * 8);        \
      const uint64_t mhi = *(const uint64_t*)(mrow + (K0) + 32 + quad * 8);   \
      if (!__all((mlo | mhi) == 0)) {                                         \
        _Pragma("unroll") for (int j = 0; j < 4; ++j) {                       \
          const uint64_t mm = (j & 2) ? mhi : mlo;                            \
          _Pragma("unroll") for (int r = 0; r < 4; ++r)                       \
            if ((mm >> (((j & 1) * 4 + r) * 8)) & 0xff) {                     \
              S[0][j][r] = 0.f;                                               \
              S[1][j][r] = 0.f;                                               \
            }                                                                 \
        }                                                                     \
      }                                                                       \
    }                                                                         \
    bf16x8 pa[2][2];                                                          \
    _Pragma("unroll") for (int u = 0; u < 2; ++u)                             \
      _Pragma("unroll") for (int f = 0; f < 2; ++f)                           \
        _Pragma("unroll") for (int e = 0; e < 8; ++e)                         \
          pa[u][f][e] = (bf16_t)S[u][2 * f + (e >> 2)][e & 3];                \
    _Pragma("unroll") for (int u = 0; u < 2; ++u) {                           \
      Ol[u] = mfma_16x16x32(pa[u][0], ones, Ol[u]);                           \
      Ol[u] = mfma_16x16x32(pa[u][1], ones, Ol[u]);                           \
    }                                                                         \
    _Pragma("unroll") for (int jd = 0; jd < 4; ++jd) {                        \
      const bf16x8 vb0 = *(const bf16x8*)(Vc + oA + jd * 1024);               \
      const bf16x8 vb1 = *(const bf16x8*)(Vc + oB + jd * 1024);               \
      _Pragma("unroll") for (int u = 0; u < 2; ++u) {                         \
        O[u][jd] = mfma_16x16x32(pa[u][0], vb0, O[u][jd]);                    \
        O[u][jd] = mfma_16x16x32(pa[u][1], vb1, O[u][jd]);                    \
      }                                                                       \
    }                                                                         \
  }

__global__ __launch_bounds__(256, 4) void attn_kernel(const bf16_t* __restrict__ qt,
                                                      const bf16_t* __restrict__ kt,
                                                      const bf16_t* __restrict__ vt,
                                                      const unsigned char* __restrict__ mask,
                                                      bf16_t* __restrict__ ctx) {
  __shared__ bf16_t Kl[2][64 * 64];        // [pos][d], col-blocks swizzled by pos&7
  __shared__ bf16_t Vl[2][64 * 64];        // [d][kk],  col-blocks swizzled by d&7
  __shared__ int mflag;
  // XCD remap: XCD a <- bh in [8a,8a+8), all 16 q-tiles (bijective over 1024)
  const int L  = blockIdx.x + (blockIdx.y << 4);
  const int bh = ((L & 7) << 3) | ((L >> 3) & 7);
  const int q0 = (L >> 6) * 128;
  const int b = bh >> 4, h = bh & (NH - 1);
  const int tid = threadIdx.x;
  const int wave = tid >> 6, lane = tid & 63;
  const int quad = lane >> 4, l16 = lane & 15;
  const float scale_l2e = 0.125f * 1.44269504f;  // HD^-0.5 * log2(e)

  const bf16_t* kbase = kt + (size_t)bh * LSEQ * HD;
  const bf16_t* vbase = vt + (size_t)bh * HD * LSEQ;
  const unsigned char* mrow = mask + (size_t)b * LSEQ;

  if (tid == 0) mflag = 0;
  __syncthreads();
  // mask pre-scan: 256 threads x 8B = entire 2048B row
  {
    const uint64_t mw = ((const uint64_t*)mrow)[tid];
    if (mw != 0) atomicOr(&mflag, 1);
  }

  // Q fragments (m=l16, k=quad*8+e), used as B-operand of swapped QK^T
  bf16x8 qa[2][2];
#pragma unroll
  for (int u = 0; u < 2; ++u) {
    const bf16_t* qrow = qt + (((size_t)bh * LSEQ) + q0 + wave * 32 + u * 16 + l16) * HD;
    qa[u][0] = *(const bf16x8*)(qrow + quad * 8);
    qa[u][1] = *(const bf16x8*)(qrow + 32 + quad * 8);
  }

  f32x4 O[2][4];
  f32x4 Ol[2];
#pragma unroll
  for (int u = 0; u < 2; ++u) {
    Ol[u] = (f32x4){0.f, 0.f, 0.f, 0.f};
#pragma unroll
    for (int j = 0; j < 4; ++j) O[u][j] = (f32x4){0.f, 0.f, 0.f, 0.f};
  }
  bf16x8 ones;
#pragma unroll
  for (int e = 0; e < 8; ++e) ones[e] = (bf16_t)1.0f;

  // --- hoisted per-lane offsets ---
  const int srow8 = lane >> 3;  // 0..7 within 8-row chunk
  const int scb   = lane & 7;   // LDS col-block position
  const int c0 = wave * 2, c1 = c0 + 1;
  const int p0 = c0 * 8 + srow8, p1 = p0 + 8;
  const int g0 = (scb ^ srow8) * 8;   // p&7 == srow8 for both chunks
  const int sig0 = ((p0 >> 5) << 5) | (((p0 >> 2) & 3) << 3) | (((p0 >> 4) & 1) << 2) | (p0 & 3);
  const int sig1 = ((p1 >> 5) << 5) | (((p1 >> 2) & 3) << 3) | (((p1 >> 4) & 1) << 2) | (p1 & 3);
  const int kgo0 = sig0 * HD + g0, kgo1 = sig1 * HD + g0;      // K global lane offsets
  const int vgo0 = p0 * LSEQ + g0, vgo1 = p1 * LSEQ + g0;      // V global lane offsets
  const int ld0 = c0 * 512, ld1 = c1 * 512;                    // LDS dst offsets

  // fragment-read offsets: sw = (j*16+l16)&7 == l16&7 for all j
  const int sw  = l16 & 7;
  const int oA  = l16 * 64 + ((quad ^ sw) << 3);
  const int oB  = l16 * 64 + (((quad + 4) ^ sw) << 3);

  // prologue: stage tiles 0 and 1 (K rows sigma-permuted); 8 loads in flight
  GLD16(kbase + kgo0, &Kl[0][0] + ld0);
  GLD16(kbase + kgo1, &Kl[0][0] + ld1);
  GLD16(vbase + vgo0, &Vl[0][0] + ld0);
  GLD16(vbase + vgo1, &Vl[0][0] + ld1);
  GLD16(kbase + (size_t)64 * HD + kgo0, &Kl[1][0] + ld0);
  GLD16(kbase + (size_t)64 * HD + kgo1, &Kl[1][0] + ld1);
  GLD16(vbase + (size_t)(vgo0 + 64), &Vl[1][0] + ld0);
  GLD16(vbase + (size_t)(vgo1 + 64), &Vl[1][0] + ld1);

  // non-draining mflag sync: own atomic done (lgkm), then barrier, then read
  WAITL0; SBAR;
  const bool has_mask = (mflag != 0);

  int cur = 0;
  for (int t = 0; t < 30; ++t) {
    WAITV4; SBAR; SCHED0;
    ATTN_TILE(t * 64);
    WAITL0; SBAR; SCHED0;
    {
      const int k0n = t * 64 + 128;
      bf16_t* Kd = &Kl[cur][0];
      bf16_t* Vd = &Vl[cur][0];
      GLD16(kbase + (size_t)k0n * HD + kgo0, Kd + ld0);
      GLD16(kbase + (size_t)k0n * HD + kgo1, Kd + ld1);
      GLD16(vbase + (size_t)(vgo0 + k0n), Vd + ld0);
      GLD16(vbase + (size_t)(vgo1 + k0n), Vd + ld1);
    }
    cur ^= 1;
  }
  // t=30: own loads are oldest 4 of 8
  WAITV4; SBAR; SCHED0;
  ATTN_TILE(30 * 64);
  cur ^= 1;
  // t=31: last tile
  WAITV0; SBAR; SCHED0;
  ATTN_TILE(31 * 64);

  // epilogue: normalize and write ctx [B, LSEQ, NH*HD] bf16 (token-major)
#pragma unroll
  for (int u = 0; u < 2; ++u) {
    f32x4 linv;
#pragma unroll
    for (int r = 0; r < 4; ++r) linv[r] = 1.0f / Ol[u][r];
#pragma unroll
    for (int jd = 0; jd < 4; ++jd)
#pragma unroll
      for (int r = 0; r < 4; ++r) {
        const int l = q0 + wave * 32 + u * 16 + quad * 4 + r;
        const int d = h * HD + jd * 16 + l16;
        const float o = O[u][jd][r] * linv[r];
        ctx[((size_t)b * LSEQ + l) * DM + d] = (bf16_t)o;
      }
  }
}

// ---------------------------------------------------------------------------
extern "C" void kernel_launch(void* const* d_in, const int* in_sizes, int n_in,
                              void* d_out, int out_size, void* d_ws, size_t ws_size,
                              hipStream_t stream) {
  (void)in_sizes; (void)n_in; (void)out_size; (void)ws_size;
  const float* query = (const float*)d_in[0];
  const float* key   = (const float*)d_in[1];
  const float* value = (const float*)d_in[2];
  const float* cos_q = (const float*)d_in[3];
  const float* sin_q = (const float*)d_in[4];
  const float* cos_k = (const float*)d_in[5];
  const float* sin_k = (const float*)d_in[6];
  const unsigned char* mask = (const unsigned char*)d_in[7];
  const float* Wq = (const float*)d_in[8];
  const float* bq = (const float*)d_in[9];
  const float* Wk = (const float*)d_in[10];
  const float* bk = (const float*)d_in[11];
  const float* Wv = (const float*)d_in[12];
  const float* bv = (const float*)d_in[13];
  const float* Wo = (const float*)d_in[14];
  const float* bo = (const float*)d_in[15];
  float* out = (float*)d_out;

  const size_t ACT = (size_t)TOKENS * DM;  // 8388608
  const size_t WEL = (size_t)DM * DM;      // 1048576
  const size_t CSN = (size_t)TOKENS * HD;  // 524288 float2 per table

  bf16_t* p   = (bf16_t*)d_ws;
  bf16_t* xq  = p; p += ACT;    // xq,xk,xv contiguous (prep dst / qkv A base)
  bf16_t* xk  = p; p += ACT;
  bf16_t* xv  = p; p += ACT;
  bf16_t* wqb = p; p += WEL;    // wqb..wob contiguous (prep dst / qkv W base)
  bf16_t* wkb = p; p += WEL;
  bf16_t* wvb = p; p += WEL;
  bf16_t* wob = p; p += WEL;
  bf16_t* qtb = p; p += ACT;
  bf16_t* ktb = p; p += ACT;
  bf16_t* vtb = p; p += ACT;
  bf16_t* ctx = xk;  // alias: xk dead after qkv proj
  (void)xv; (void)wkb; (void)wvb;

  // cos/sin float2 tables live in d_out (32MB f32): only out_gemm writes
  // d_out, at the very end — free scratch until then.
  float2* csq = (float2*)out;        // 4MB
  float2* csk = csq + CSN;           // 4MB

  // fused prep: casts + cs-table build, ONE dispatch
  prep_kernel<<<dim3(29696), 256, 0, stream>>>(query, key, value, Wq, Wk, Wv, Wo,
                                               cos_q, sin_q, cos_k, sin_k,
                                               xq, wqb, csq);

  // fused q/k/v projections (one dispatch, z = which projection)
  qkv_proj_kernel<<<dim3(TOKENS / 128, DM / 128, 3), 256, 0, stream>>>(
      xq, wqb, bq, bk, bv, csq, csk, qtb, ktb, vtb);

  // flash attention -> ctx [B, LSEQ, DM] bf16
  attn_kernel<<<dim3(LSEQ / 128, B_DIM * NH), 256, 0, stream>>>(qtb, ktb, vtb, mask, ctx);

  // output projection -> f32 d_out (overwrites the cs scratch)
  out_gemm_kernel<<<dim3(TOKENS / 128, DM / 128), 256, 0, stream>>>(ctx, wob, bo, out);
}